// Round 7
// baseline (894.026 us; speedup 1.0000x reference)
//
#include <hip/hip_runtime.h>

#define NN 100000
#define NE 1200000
#define CH 64
#define NREL 5
#define NCLS 8
#define SLOT 64      // max in-degree tracked; deg ~ Poisson(12), P(>64) ~ 1e-30
#define BN 128       // nodes per block
#define KTOT 384     // 6*64 (root + 5 relations)
#define HPAD 66      // padded h2-stage stride (floats)

typedef _Float16 f16;
typedef _Float16 f16x4 __attribute__((ext_vector_type(4)));
typedef _Float16 f16x8 __attribute__((ext_vector_type(8)));
typedef float f32x4 __attribute__((ext_vector_type(4)));

// ---- x (f32) -> f16 ----
__global__ __launch_bounds__(256) void cvt_f16_kernel(const float* __restrict__ x,
                                                      f16* __restrict__ xh) {
    int t = blockIdx.x * 256 + threadIdx.x;
    if (t >= NN * CH / 4) return;
    float4 v = reinterpret_cast<const float4*>(x)[t];
    f16x4 h = {(f16)v.x, (f16)v.y, (f16)v.z, (f16)v.w};
    *reinterpret_cast<f16x4*>(xh + (size_t)t * 4) = h;
}

// ---- build per-dst edge lists: sorted[d*SLOT+k] = src | (rel<<17) ----
__global__ __launch_bounds__(256) void scatter_kernel(const int* __restrict__ src,
                                                      const int* __restrict__ dst,
                                                      const int* __restrict__ et,
                                                      int* __restrict__ cursor,
                                                      int* __restrict__ sorted) {
    int e = blockIdx.x * 256 + threadIdx.x;
    if (e >= NE) return;
    int d = dst[e];
    int pos = atomicAdd(&cursor[d], 1);
    if (pos < SLOT) sorted[(size_t)d * SLOT + pos] = src[e] | (et[e] << 17);
}

// ---- convert weights to f16 B^T layout: Btg[layer][n][k] ----
__global__ __launch_bounds__(256) void prep_weights(const float* __restrict__ root1,
                                                    const float* __restrict__ W1,
                                                    const float* __restrict__ root2,
                                                    const float* __restrict__ W2,
                                                    f16* __restrict__ Btg) {
    int o = blockIdx.x * 256 + threadIdx.x;
    if (o >= 2 * 64 * KTOT) return;
    int layer = o / (64 * KTOT);
    int rem = o % (64 * KTOT);
    int n = rem / KTOT, k = rem % KTOT;
    const float* R = layer ? root2 : root1;
    const float* W = layer ? W2 : W1;
    float v = (k < CH) ? R[k * CH + n] : W[(size_t)(k - CH) * CH + n];
    Btg[o] = (f16)v;
}

// One block = 128 nodes.
// Phase 1: branch-free gather. Wave owns 8 A-panel rows; edge words lane-resident;
//          2 edges/instr (half-waves, 2 ch/lane) accumulated via ds_pk_add_f16.
// Phase 2: MFMA [128x384]x[384x64], bias in C-init.
// Epilogue: relu+f16 store (layer1) or f32 out + fused classifier (layer2).
template<bool RELU, bool CLS>
__global__ __launch_bounds__(1024, 4) void fused_layer(
    const f16* __restrict__ in, const f16* __restrict__ Btg,
    const float* __restrict__ bias,
    const int* __restrict__ cursor, const int* __restrict__ sorted,
    float* __restrict__ outf, f16* __restrict__ outh,
    const float* __restrict__ Wc, const float* __restrict__ bc,
    float* __restrict__ logits) {
    __shared__ f16 Bt[64 * 400];       // 51200 B  weights [n][k], 800B padded rows
    __shared__ f16 Ap[BN * 400];       // 102400 B A-panel [node][k], 800B padded rows
    __shared__ float scl[BN][NREL];    // 2560 B   per-(node,rel) 1/cnt
    __shared__ float WcL[CH * NCLS];   // 2 KB

    const int tid = threadIdx.x;
    const int wv = tid >> 6, lane = tid & 63;
    const int half = lane >> 5;        // which edge of the pair
    const int ch2 = lane & 31;         // channel-pair index (2 f16 per lane)
    const int nb0 = blockIdx.x * BN;

    // stage this layer's weights: one layer = 64*KTOT f16 = 64*KTOT*2 bytes = 3072 x 16B chunks
    for (int c = tid; c < (64 * KTOT * 2) / 16; c += 1024) {
        int n = c / 48, off = c % 48;  // 48 chunks per 768B row
        *(float4*)((char*)Bt + n * 800 + off * 16) =
            *(const float4*)((const char*)Btg + (size_t)c * 16);
    }
    if (CLS) {
        for (int i = tid; i < CH * NCLS; i += 1024) WcL[i] = Wc[i];
    }

    // zero this wave's A-panel relation slots (bytes 128..768 of each row)
    {
        uint4 z = {0, 0, 0, 0};
        for (int q = 0; q < 8; ++q) {
            int nl = wv * 8 + q;
            if (lane < 40) *(uint4*)((char*)Ap + nl * 800 + 128 + lane * 16) = z;
        }
    }
    asm volatile("" ::: "memory");  // zero-init ordered before atomic adds

    const uint apO = (uint)(size_t)(void*)&Ap[0];
    const uint zpk = 0u;

    // ---- phase 1: gather ----
    for (int q = 0; q < 8; ++q) {
        int nl = wv * 8 + q;
        int i = nb0 + nl;
        if (i >= NN) {
            Ap[nl * 400 + lane] = (f16)0.f;      // self slot
            if (lane < NREL) scl[nl][lane] = 1.f;
            continue;
        }
        int deg = cursor[i];
        if (deg > SLOT) deg = SLOT;
        const int* sp = sorted + (size_t)i * SLOT;
        int wlane = sp[lane];                    // all edge words lane-resident (256B)
        uint rl = (uint)wlane >> 17;
        bool vl = lane < deg;

        // counts via ballots (branch-free)
        int c0 = (int)__popcll(__ballot(vl && rl == 0));
        int c1 = (int)__popcll(__ballot(vl && rl == 1));
        int c2 = (int)__popcll(__ballot(vl && rl == 2));
        int c3 = (int)__popcll(__ballot(vl && rl == 3));
        int c4 = (int)__popcll(__ballot(vl && rl == 4));
        int cc = c0;
        cc = (lane == 1) ? c1 : cc; cc = (lane == 2) ? c2 : cc;
        cc = (lane == 3) ? c3 : cc; cc = (lane == 4) ? c4 : cc;
        if (lane < NREL) scl[nl][lane] = 1.0f / fmaxf((float)cc, 1.0f);

        // self row -> slot 0
        {
            float sv = (float)in[(size_t)i * CH + lane];
            if (RELU) sv = fmaxf(sv, 0.f);
            Ap[nl * 400 + lane] = (f16)sv;
        }

        // edges: 2 per instruction (half-waves), unroll 4 -> 8 edges in flight
        const uint rowbase = apO + (uint)nl * 800u + 128u + (uint)ch2 * 4u;
        int npairs = (deg + 1) >> 1;
        for (int p0 = 0; p0 < npairs; p0 += 4) {
#pragma unroll
            for (int u = 0; u < 4; ++u) {
                int e = 2 * (p0 + u) + half;
                int w = __shfl(wlane, e & 63);
                bool val = e < deg;
                uint rr = val ? ((uint)w >> 17) : 0u;
                uint ss = val ? ((uint)w & 0x1FFFF) : 0u;
                uint v = *(const uint*)((const char*)in + (size_t)ss * 128 + ch2 * 4);
                if (RELU) {
                    // packed f16 relu with explicit zero VGPR (exact both-halves semantics)
                    asm("v_pk_max_f16 %0, %1, %2" : "=v"(v) : "v"(v), "v"(zpk));
                }
                v = val ? v : 0u;
                uint a = rowbase + rr * 128u;
                asm volatile("ds_pk_add_f16 %0, %1" :: "v"(a), "v"(v));
            }
        }
    }
    asm volatile("" ::: "memory");  // adds ordered before normalize reads (same-wave DS in-order)

    // normalize wave's rows by 1/cnt
    for (int q = 0; q < 8; ++q) {
        int nl = wv * 8 + q;
#pragma unroll
        for (int m = 1; m < 6; ++m) {
            float sc = scl[nl][m - 1];
            f16 t = Ap[nl * 400 + m * 64 + lane];
            Ap[nl * 400 + m * 64 + lane] = (f16)((float)t * sc);
        }
    }
    __syncthreads();

    // ---- phase 2: MFMA. wave w: M-tile tm = w>>1, N-tiles tn, tn+1 ----
    const int tm = wv >> 1;
    const int tn = (wv & 1) * 2;
    const int col = lane & 15, lg = lane >> 4;
    float bv0 = bias[tn * 16 + col];
    float bv1 = bias[tn * 16 + 16 + col];
    f32x4 acc0 = {bv0, bv0, bv0, bv0};
    f32x4 acc1 = {bv1, bv1, bv1, bv1};
    const char* Ab = (const char*)Ap + (tm * 16 + col) * 800 + lg * 16;
    const char* Bb0 = (const char*)Bt + (tn * 16 + col) * 800 + lg * 16;
    const char* Bb1 = Bb0 + 16 * 800;
#pragma unroll
    for (int k = 0; k < KTOT / 32; ++k) {
        f16x8 af = *(const f16x8*)(Ab + k * 64);
        f16x8 bf0 = *(const f16x8*)(Bb0 + k * 64);
        f16x8 bf1 = *(const f16x8*)(Bb1 + k * 64);
        acc0 = __builtin_amdgcn_mfma_f32_16x16x32_f16(af, bf0, acc0, 0, 0, 0);
        acc1 = __builtin_amdgcn_mfma_f32_16x16x32_f16(af, bf1, acc1, 0, 0, 0);
    }

    if (!CLS) {
#pragma unroll
        for (int r = 0; r < 4; ++r) {
            int node = nb0 + tm * 16 + lg * 4 + r;
            if (node < NN) {
                outh[(size_t)node * CH + tn * 16 + col] = (f16)fmaxf(acc0[r], 0.f);
                outh[(size_t)node * CH + (tn + 1) * 16 + col] = (f16)fmaxf(acc1[r], 0.f);
            }
        }
    } else {
        __syncthreads();  // Ap reads done; reuse as h-stage
        float* hst = (float*)Ap;  // [BN][HPAD]
        float bcr[NCLS];
#pragma unroll
        for (int c = 0; c < NCLS; ++c) bcr[c] = bc[c];
#pragma unroll
        for (int r = 0; r < 4; ++r) {
            int nloc = tm * 16 + lg * 4 + r;
            int node = nb0 + nloc;
            hst[nloc * HPAD + tn * 16 + col] = acc0[r];
            hst[nloc * HPAD + (tn + 1) * 16 + col] = acc1[r];
            if (node < NN) {
                outf[(size_t)node * CH + tn * 16 + col] = acc0[r];
                outf[(size_t)node * CH + (tn + 1) * 16 + col] = acc1[r];
            }
        }
        __syncthreads();
        for (int q = 0; q < 8; ++q) {
            int nl = wv * 8 + q;
            int i = nb0 + nl;
            if (i >= NN) continue;
            float v = hst[nl * HPAD + lane];
            float p[NCLS];
#pragma unroll
            for (int c = 0; c < NCLS; ++c) p[c] = v * WcL[lane * NCLS + c];
#pragma unroll
            for (int off = 32; off > 0; off >>= 1) {
#pragma unroll
                for (int c = 0; c < NCLS; ++c) p[c] += __shfl_xor(p[c], off);
            }
            if (lane == 0) {
                float4 lo = make_float4(p[0] + bcr[0], p[1] + bcr[1], p[2] + bcr[2], p[3] + bcr[3]);
                float4 hi = make_float4(p[4] + bcr[4], p[5] + bcr[5], p[6] + bcr[6], p[7] + bcr[7]);
                *reinterpret_cast<float4*>(&logits[(size_t)i * NCLS]) = lo;
                *reinterpret_cast<float4*>(&logits[(size_t)i * NCLS + 4]) = hi;
            }
        }
    }
}

extern "C" void kernel_launch(void* const* d_in, const int* in_sizes, int n_in,
                              void* d_out, int out_size, void* d_ws, size_t ws_size,
                              hipStream_t stream) {
    const float* x     = (const float*)d_in[0];
    const int*   ei    = (const int*)d_in[1];
    const int*   et    = (const int*)d_in[2];
    const float* W1    = (const float*)d_in[3];
    const float* root1 = (const float*)d_in[4];
    const float* b1    = (const float*)d_in[5];
    const float* W2    = (const float*)d_in[6];
    const float* root2 = (const float*)d_in[7];
    const float* b2    = (const float*)d_in[8];
    const float* Wc    = (const float*)d_in[9];
    const float* bc    = (const float*)d_in[10];
    const int* src = ei;
    const int* dst = ei + NE;

    float* h2     = (float*)d_out;            // [NN][CH]
    float* logits = h2 + (size_t)NN * CH;     // [NN][NCLS]

    int* cursor = (int*)d_ws;                                   // [NN]
    int* sorted = cursor + NN;                                  // [NN][SLOT] + 16 slack
    f16* h1h    = (f16*)(sorted + (size_t)NN * SLOT + 16);      // [NN][CH]
    f16* xh     = h1h + (size_t)NN * CH;                        // [NN][CH]
    f16* Btg    = xh + (size_t)NN * CH;                         // [2][64][KTOT]

    (void)hipMemsetAsync(cursor, 0, (size_t)NN * 4, stream);
    cvt_f16_kernel<<<(NN * CH / 4 + 255) / 256, 256, 0, stream>>>(x, xh);
    scatter_kernel<<<(NE + 255) / 256, 256, 0, stream>>>(src, dst, et, cursor, sorted);
    prep_weights<<<(2 * 64 * KTOT + 255) / 256, 256, 0, stream>>>(root1, W1, root2, W2, Btg);

    int nBlk = (NN + BN - 1) / BN;  // 782
    fused_layer<false, false><<<nBlk, 1024, 0, stream>>>(
        xh, Btg, b1, cursor, sorted, nullptr, h1h, nullptr, nullptr, nullptr);
    fused_layer<true, true><<<nBlk, 1024, 0, stream>>>(
        h1h, Btg + (size_t)64 * KTOT, b2, cursor, sorted, h2, nullptr, Wc, bc, logits);
}

// Round 8
// 349.236 us; speedup vs baseline: 2.5599x; 2.5599x over previous
//
#include <hip/hip_runtime.h>

#define NN 100000
#define NE 1200000
#define CH 64
#define NREL 5
#define NCLS 8
#define SLOT 64      // max in-degree tracked; deg ~ Poisson(12), P(>64) ~ 1e-30
#define BN 128       // nodes per transform block
#define KTOT 384     // 6*64 (root + 5 relations)
#define HPAD 66      // padded h2-stage stride (floats)

typedef _Float16 f16;
typedef _Float16 f16x4 __attribute__((ext_vector_type(4)));
typedef _Float16 f16x8 __attribute__((ext_vector_type(8)));
typedef float f32x4 __attribute__((ext_vector_type(4)));

#define RFL __builtin_amdgcn_readfirstlane

// ---- x (f32) -> f16 ----
__global__ __launch_bounds__(256) void cvt_f16_kernel(const float* __restrict__ x,
                                                      f16* __restrict__ xh) {
    int t = blockIdx.x * 256 + threadIdx.x;
    if (t >= NN * CH / 4) return;
    float4 v = reinterpret_cast<const float4*>(x)[t];
    f16x4 h = {(f16)v.x, (f16)v.y, (f16)v.z, (f16)v.w};
    *reinterpret_cast<f16x4*>(xh + (size_t)t * 4) = h;
}

// ---- build per-dst edge lists: sorted[d*SLOT+k] = src | (rel<<17) ----
__global__ __launch_bounds__(256) void scatter_kernel(const int* __restrict__ src,
                                                      const int* __restrict__ dst,
                                                      const int* __restrict__ et,
                                                      int* __restrict__ cursor,
                                                      int* __restrict__ sorted) {
    int e = blockIdx.x * 256 + threadIdx.x;
    if (e >= NE) return;
    int d = dst[e];
    int pos = atomicAdd(&cursor[d], 1);
    if (pos < SLOT) sorted[(size_t)d * SLOT + pos] = src[e] | (et[e] << 17);
}

// ---- convert weights to f16 B^T layout: Btg[layer][n][k] ----
__global__ __launch_bounds__(256) void prep_weights(const float* __restrict__ root1,
                                                    const float* __restrict__ W1,
                                                    const float* __restrict__ root2,
                                                    const float* __restrict__ W2,
                                                    f16* __restrict__ Btg) {
    int o = blockIdx.x * 256 + threadIdx.x;
    if (o >= 2 * 64 * KTOT) return;
    int layer = o / (64 * KTOT);
    int rem = o % (64 * KTOT);
    int n = rem / KTOT, k = rem % KTOT;
    const float* R = layer ? root2 : root1;
    const float* W = layer ? W2 : W1;
    float v = (k < CH) ? R[k * CH + n] : W[(size_t)(k - CH) * CH + n];
    Btg[o] = (f16)v;
}

// ---- gather: one wave per node, no LDS, high occupancy, 8 loads in flight ----
// A[i-n0][m][lane]: m=0 self row, m=1+r relation means (f16)
__global__ __launch_bounds__(256, 8) void gather_kernel(
    const f16* __restrict__ in, const int* __restrict__ cursor,
    const int* __restrict__ sorted, f16* __restrict__ A,
    int n0, int n1) {
    int gw = (blockIdx.x * 256 + threadIdx.x) >> 6;
    int lane = threadIdx.x & 63;
    int i = n0 + gw;
    if (i >= n1) return;

    int deg = cursor[i];
    if (deg > SLOT) deg = SLOT;
    const int* sp = sorted + (size_t)i * SLOT;

    float self = (float)in[(size_t)i * CH + lane];
    float a0 = 0.f, a1 = 0.f, a2 = 0.f, a3 = 0.f, a4 = 0.f;
    int c0 = 0, c1 = 0, c2 = 0, c3 = 0, c4 = 0;

    if (deg > 0) {
        int4 pka = *(const int4*)sp;
        int4 pkb = *(const int4*)(sp + 4);
        for (int e0 = 0; e0 < deg; e0 += 8) {
            // prefetch next group (16-int slack after sorted guarantees in-bounds)
            int4 nxa = *(const int4*)(sp + e0 + 8);
            int4 nxb = *(const int4*)(sp + e0 + 12);
            // extract 8 edge words to SGPRs
            int p0 = RFL(pka.x), p1 = RFL(pka.y), p2 = RFL(pka.z), p3 = RFL(pka.w);
            int p4 = RFL(pkb.x), p5 = RFL(pkb.y), p6 = RFL(pkb.z), p7 = RFL(pkb.w);
            // validity (scalar); invalid edges load node's own row (safe, hot) and skip accumulate
            uint s0 = (e0 + 0 < deg) ? ((uint)p0 & 0x1FFFF) : (uint)i;
            uint s1 = (e0 + 1 < deg) ? ((uint)p1 & 0x1FFFF) : (uint)i;
            uint s2 = (e0 + 2 < deg) ? ((uint)p2 & 0x1FFFF) : (uint)i;
            uint s3 = (e0 + 3 < deg) ? ((uint)p3 & 0x1FFFF) : (uint)i;
            uint s4 = (e0 + 4 < deg) ? ((uint)p4 & 0x1FFFF) : (uint)i;
            uint s5 = (e0 + 5 < deg) ? ((uint)p5 & 0x1FFFF) : (uint)i;
            uint s6 = (e0 + 6 < deg) ? ((uint)p6 & 0x1FFFF) : (uint)i;
            uint s7 = (e0 + 7 < deg) ? ((uint)p7 & 0x1FFFF) : (uint)i;
            // issue all 8 row loads (independent -> pipelined)
            float v0 = (float)in[(size_t)s0 * CH + lane];
            float v1 = (float)in[(size_t)s1 * CH + lane];
            float v2 = (float)in[(size_t)s2 * CH + lane];
            float v3 = (float)in[(size_t)s3 * CH + lane];
            float v4 = (float)in[(size_t)s4 * CH + lane];
            float v5 = (float)in[(size_t)s5 * CH + lane];
            float v6 = (float)in[(size_t)s6 * CH + lane];
            float v7 = (float)in[(size_t)s7 * CH + lane];
            // scalar-branch accumulate ladders (r wave-uniform)
#define LAD(J, PJ, VJ)                                                          \
            if (e0 + J < deg) {                                                 \
                int r = (PJ) >> 17;                                             \
                if (r == 0)      { a0 += (VJ); c0++; }                          \
                else if (r == 1) { a1 += (VJ); c1++; }                          \
                else if (r == 2) { a2 += (VJ); c2++; }                          \
                else if (r == 3) { a3 += (VJ); c3++; }                          \
                else             { a4 += (VJ); c4++; }                          \
            }
            LAD(0, p0, v0) LAD(1, p1, v1) LAD(2, p2, v2) LAD(3, p3, v3)
            LAD(4, p4, v4) LAD(5, p5, v5) LAD(6, p6, v6) LAD(7, p7, v7)
#undef LAD
            pka = nxa; pkb = nxb;
        }
    }

    float i0 = 1.0f / (float)(c0 > 0 ? c0 : 1);
    float i1 = 1.0f / (float)(c1 > 0 ? c1 : 1);
    float i2 = 1.0f / (float)(c2 > 0 ? c2 : 1);
    float i3 = 1.0f / (float)(c3 > 0 ? c3 : 1);
    float i4 = 1.0f / (float)(c4 > 0 ? c4 : 1);

    size_t ab = (size_t)(i - n0) * KTOT;
    A[ab + 0 * CH + lane] = (f16)self;
    A[ab + 1 * CH + lane] = (f16)(a0 * i0);
    A[ab + 2 * CH + lane] = (f16)(a1 * i1);
    A[ab + 3 * CH + lane] = (f16)(a2 * i2);
    A[ab + 4 * CH + lane] = (f16)(a3 * i3);
    A[ab + 5 * CH + lane] = (f16)(a4 * i4);
}

// ---- transform: [chunk x 384] x [384 x 64] MFMA, A staged from global ----
// Epilogue: relu+f16 store (layer1) or f32 out + fused classifier (layer2).
template<bool CLS>
__global__ __launch_bounds__(1024, 1) void transform_kernel(
    const f16* __restrict__ A, const f16* __restrict__ Btg,
    const float* __restrict__ bias,
    float* __restrict__ outf, f16* __restrict__ outh,
    const float* __restrict__ Wc, const float* __restrict__ bc,
    float* __restrict__ logits, int n0, int n1) {
    __shared__ f16 Bt[64 * 400];       // 51200 B  weights [n][k], 800B padded rows
    __shared__ f16 Ap[BN * 400];       // 102400 B A-panel [node][k], 800B padded rows
    __shared__ float WcL[CH * NCLS];   // 2 KB

    const int tid = threadIdx.x;
    const int wv = tid >> 6, lane = tid & 63;
    const int lb0 = blockIdx.x * BN;   // local (A-buffer) node base
    const int nb0 = n0 + lb0;          // global node base

    // stage weights: 64 rows x 48 chunks = 3072 x 16B
    for (int c = tid; c < 3072; c += 1024) {
        int n = c / 48, off = c % 48;
        *(float4*)((char*)Bt + n * 800 + off * 16) =
            *(const float4*)((const char*)Btg + (size_t)c * 16);
    }
    // stage A-panel: 128 rows x 48 chunks = 6144 x 16B (sequential global reads)
    const char* Asrc = (const char*)A + (size_t)lb0 * 768;
    for (int c = tid; c < 6144; c += 1024) {
        int n = c / 48, off = c % 48;
        *(float4*)((char*)Ap + n * 800 + off * 16) =
            *(const float4*)(Asrc + (size_t)n * 768 + off * 16);
    }
    if (CLS) {
        for (int i2 = tid; i2 < CH * NCLS; i2 += 1024) WcL[i2] = Wc[i2];
    }
    __syncthreads();

    // MFMA: wave w -> M-tile tm = w>>1 (16 nodes), N-tiles tn, tn+1
    const int tm = wv >> 1;
    const int tn = (wv & 1) * 2;
    const int col = lane & 15, lg = lane >> 4;
    float bv0 = bias[tn * 16 + col];
    float bv1 = bias[tn * 16 + 16 + col];
    f32x4 acc0 = {bv0, bv0, bv0, bv0};
    f32x4 acc1 = {bv1, bv1, bv1, bv1};
    const char* Ab = (const char*)Ap + (tm * 16 + col) * 800 + lg * 16;
    const char* Bb0 = (const char*)Bt + (tn * 16 + col) * 800 + lg * 16;
    const char* Bb1 = Bb0 + 16 * 800;
#pragma unroll
    for (int k = 0; k < KTOT / 32; ++k) {
        f16x8 af = *(const f16x8*)(Ab + k * 64);
        f16x8 bf0 = *(const f16x8*)(Bb0 + k * 64);
        f16x8 bf1 = *(const f16x8*)(Bb1 + k * 64);
        acc0 = __builtin_amdgcn_mfma_f32_16x16x32_f16(af, bf0, acc0, 0, 0, 0);
        acc1 = __builtin_amdgcn_mfma_f32_16x16x32_f16(af, bf1, acc1, 0, 0, 0);
    }

    if (!CLS) {
#pragma unroll
        for (int r = 0; r < 4; ++r) {
            int node = nb0 + tm * 16 + lg * 4 + r;
            if (node < n1) {
                outh[(size_t)node * CH + tn * 16 + col] = (f16)fmaxf(acc0[r], 0.f);
                outh[(size_t)node * CH + (tn + 1) * 16 + col] = (f16)fmaxf(acc1[r], 0.f);
            }
        }
    } else {
        __syncthreads();  // Ap reads done; reuse as h-stage
        float* hst = (float*)Ap;  // [BN][HPAD]
        float bcr[NCLS];
#pragma unroll
        for (int c = 0; c < NCLS; ++c) bcr[c] = bc[c];
#pragma unroll
        for (int r = 0; r < 4; ++r) {
            int nloc = tm * 16 + lg * 4 + r;
            int node = nb0 + nloc;
            hst[nloc * HPAD + tn * 16 + col] = acc0[r];
            hst[nloc * HPAD + (tn + 1) * 16 + col] = acc1[r];
            if (node < n1) {
                outf[(size_t)node * CH + tn * 16 + col] = acc0[r];
                outf[(size_t)node * CH + (tn + 1) * 16 + col] = acc1[r];
            }
        }
        __syncthreads();
        for (int q = 0; q < 8; ++q) {
            int nl = wv * 8 + q;
            int i = nb0 + nl;
            if (i >= n1) continue;
            float v = hst[nl * HPAD + lane];
            float p[NCLS];
#pragma unroll
            for (int c = 0; c < NCLS; ++c) p[c] = v * WcL[lane * NCLS + c];
#pragma unroll
            for (int off = 32; off > 0; off >>= 1) {
#pragma unroll
                for (int c = 0; c < NCLS; ++c) p[c] += __shfl_xor(p[c], off);
            }
            if (lane == 0) {
                float4 lo = make_float4(p[0] + bcr[0], p[1] + bcr[1], p[2] + bcr[2], p[3] + bcr[3]);
                float4 hi = make_float4(p[4] + bcr[4], p[5] + bcr[5], p[6] + bcr[6], p[7] + bcr[7]);
                *reinterpret_cast<float4*>(&logits[(size_t)i * NCLS]) = lo;
                *reinterpret_cast<float4*>(&logits[(size_t)i * NCLS + 4]) = hi;
            }
        }
    }
}

extern "C" void kernel_launch(void* const* d_in, const int* in_sizes, int n_in,
                              void* d_out, int out_size, void* d_ws, size_t ws_size,
                              hipStream_t stream) {
    const float* x     = (const float*)d_in[0];
    const int*   ei    = (const int*)d_in[1];
    const int*   et    = (const int*)d_in[2];
    const float* W1    = (const float*)d_in[3];
    const float* root1 = (const float*)d_in[4];
    const float* b1    = (const float*)d_in[5];
    const float* W2    = (const float*)d_in[6];
    const float* root2 = (const float*)d_in[7];
    const float* b2    = (const float*)d_in[8];
    const float* Wc    = (const float*)d_in[9];
    const float* bc    = (const float*)d_in[10];
    const int* src = ei;
    const int* dst = ei + NE;

    float* h2     = (float*)d_out;            // [NN][CH]
    float* logits = h2 + (size_t)NN * CH;     // [NN][NCLS]

    int* cursor = (int*)d_ws;                                   // [NN]
    int* sorted = cursor + NN;                                  // [NN][SLOT] + 16 slack
    f16* h1h    = (f16*)(sorted + (size_t)NN * SLOT + 16);      // [NN][CH]
    f16* xh     = h1h + (size_t)NN * CH;                        // [NN][CH]
    f16* Btg    = xh + (size_t)NN * CH;                         // [2][64][KTOT]
    f16* Abuf   = Btg + (size_t)2 * 64 * KTOT;                  // [nchunk][6][CH]

    // chunk sizing from available workspace
    size_t fixedB = (size_t)NN * 4 + ((size_t)NN * SLOT + 16) * 4 +
                    (size_t)NN * CH * 2 * 2 + (size_t)2 * 64 * KTOT * 2;
    size_t availB = ws_size > fixedB ? ws_size - fixedB : 0;
    long long nchunkL = (long long)(availB / (KTOT * 2));
    int nchunk = (int)((nchunkL / BN) * BN);
    int maxChunk = ((NN + BN - 1) / BN) * BN;
    if (nchunk > maxChunk) nchunk = maxChunk;
    if (nchunk < BN) nchunk = BN;  // ws_size >= ~52MB in practice; minimal fallback

    (void)hipMemsetAsync(cursor, 0, (size_t)NN * 4, stream);
    cvt_f16_kernel<<<(NN * CH / 4 + 255) / 256, 256, 0, stream>>>(x, xh);
    scatter_kernel<<<(NE + 255) / 256, 256, 0, stream>>>(src, dst, et, cursor, sorted);
    prep_weights<<<(2 * 64 * KTOT + 255) / 256, 256, 0, stream>>>(root1, W1, root2, W2, Btg);

    // ---- layer 1 ----
    for (int cn0 = 0; cn0 < NN; cn0 += nchunk) {
        int cn1 = (NN - cn0 < nchunk) ? NN : cn0 + nchunk;
        int nodes = cn1 - cn0;
        gather_kernel<<<(nodes + 3) / 4, 256, 0, stream>>>(xh, cursor, sorted, Abuf, cn0, cn1);
        transform_kernel<false><<<(nodes + BN - 1) / BN, 1024, 0, stream>>>(
            Abuf, Btg, b1, nullptr, h1h, nullptr, nullptr, nullptr, cn0, cn1);
    }
    // ---- layer 2 (+ fused classifier) ----
    for (int cn0 = 0; cn0 < NN; cn0 += nchunk) {
        int cn1 = (NN - cn0 < nchunk) ? NN : cn0 + nchunk;
        int nodes = cn1 - cn0;
        gather_kernel<<<(nodes + 3) / 4, 256, 0, stream>>>(h1h, cursor, sorted, Abuf, cn0, cn1);
        transform_kernel<true><<<(nodes + BN - 1) / BN, 1024, 0, stream>>>(
            Abuf, Btg + (size_t)64 * KTOT, b2, h2, nullptr, Wc, bc, logits, cn0, cn1);
    }
}

// Round 9
// 295.377 us; speedup vs baseline: 3.0267x; 1.1823x over previous
//
#include <hip/hip_runtime.h>

#define NN 100000
#define NE 1200000
#define CH 64
#define NREL 5
#define NCLS 8
#define SLOT 64      // max in-degree tracked; deg ~ Poisson(12), P(>64) ~ 1e-30
#define KTOT 384     // 6*64 (root + 5 relations)
#define HPAD 66      // padded h-stage stride (floats)

typedef _Float16 f16;
typedef _Float16 f16x4 __attribute__((ext_vector_type(4)));
typedef _Float16 f16x8 __attribute__((ext_vector_type(8)));
typedef float f32x4 __attribute__((ext_vector_type(4)));

#define RFL __builtin_amdgcn_readfirstlane

// ---- x (f32) -> f16 ----
__global__ __launch_bounds__(256) void cvt_f16_kernel(const float* __restrict__ x,
                                                      f16* __restrict__ xh) {
    int t = blockIdx.x * 256 + threadIdx.x;
    if (t >= NN * CH / 4) return;
    float4 v = reinterpret_cast<const float4*>(x)[t];
    f16x4 h = {(f16)v.x, (f16)v.y, (f16)v.z, (f16)v.w};
    *reinterpret_cast<f16x4*>(xh + (size_t)t * 4) = h;
}

// ---- build per-dst edge lists: sorted[d*SLOT+k] = src | (rel<<17) ----
__global__ __launch_bounds__(256) void scatter_kernel(const int* __restrict__ src,
                                                      const int* __restrict__ dst,
                                                      const int* __restrict__ et,
                                                      int* __restrict__ cursor,
                                                      int* __restrict__ sorted) {
    int e = blockIdx.x * 256 + threadIdx.x;
    if (e >= NE) return;
    int d = dst[e];
    int pos = atomicAdd(&cursor[d], 1);
    if (pos < SLOT) sorted[(size_t)d * SLOT + pos] = src[e] | (et[e] << 17);
}

// ---- convert weights to f16 B^T layout: Btg[layer][n][k] ----
__global__ __launch_bounds__(256) void prep_weights(const float* __restrict__ root1,
                                                    const float* __restrict__ W1,
                                                    const float* __restrict__ root2,
                                                    const float* __restrict__ W2,
                                                    f16* __restrict__ Btg) {
    int o = blockIdx.x * 256 + threadIdx.x;
    if (o >= 2 * 64 * KTOT) return;
    int layer = o / (64 * KTOT);
    int rem = o % (64 * KTOT);
    int n = rem / KTOT, k = rem % KTOT;
    const float* R = layer ? root2 : root1;
    const float* W = layer ? W2 : W1;
    float v = (k < CH) ? R[k * CH + n] : W[(size_t)(k - CH) * CH + n];
    Btg[o] = (f16)v;
}

// One block = 16 nodes, 256 threads (4 waves), ~12.5 KB LDS -> 8 blocks/CU.
// Phase 1: wave w gathers nodes w*4..w*4+3 (8 loads in flight) -> f16 A-panel in LDS.
// Phase 2: wave w computes N-tile w: 12x mfma_16x16x32_f16; A from LDS, B from
//          global (48 KB panel, identical across blocks -> L2-resident).
// Epilogue: relu+f16 store (layer1) or f32 out + fused classifier (layer2).
template<bool CLS>
__global__ __launch_bounds__(256, 8) void fused_layer2(
    const f16* __restrict__ in, const f16* __restrict__ Btg,
    const float* __restrict__ bias,
    const int* __restrict__ cursor, const int* __restrict__ sorted,
    float* __restrict__ outf, f16* __restrict__ outh,
    const float* __restrict__ Wc, const float* __restrict__ bc,
    float* __restrict__ logits) {
    // A-panel: 16 rows x 784 B (392 f16) = 12544 B. 784B stride -> 2-way bank
    // conflict on ds_read_b128 (free, m136). Reused as f32 h-stage for CLS.
    __shared__ __align__(16) char smem[16 * 784];
    f16* Ap = (f16*)smem;

    const int tid = threadIdx.x;
    const int wv = tid >> 6, lane = tid & 63;
    const int nb0 = blockIdx.x * 16;

    // ---- phase 1: gather 4 nodes per wave ----
    for (int q = 0; q < 4; ++q) {
        int nl = wv * 4 + q;
        int i = nb0 + nl;
        f16* arow = Ap + nl * 392;
        if (i >= NN) {
#pragma unroll
            for (int m = 0; m < 6; ++m) arow[m * 64 + lane] = (f16)0.f;
            continue;
        }
        int deg = cursor[i];
        if (deg > SLOT) deg = SLOT;
        const int* sp = sorted + (size_t)i * SLOT;

        float self = (float)in[(size_t)i * CH + lane];
        float a0 = 0.f, a1 = 0.f, a2 = 0.f, a3 = 0.f, a4 = 0.f;
        int c0 = 0, c1 = 0, c2 = 0, c3 = 0, c4 = 0;

        if (deg > 0) {
            int4 pka = *(const int4*)sp;
            int4 pkb = *(const int4*)(sp + 4);
            for (int e0 = 0; e0 < deg; e0 += 8) {
                int4 nxa = *(const int4*)(sp + e0 + 8);   // slack guarantees in-bounds
                int4 nxb = *(const int4*)(sp + e0 + 12);
                int p0 = RFL(pka.x), p1 = RFL(pka.y), p2 = RFL(pka.z), p3 = RFL(pka.w);
                int p4 = RFL(pkb.x), p5 = RFL(pkb.y), p6 = RFL(pkb.z), p7 = RFL(pkb.w);
                uint s0 = (e0 + 0 < deg) ? ((uint)p0 & 0x1FFFF) : (uint)i;
                uint s1 = (e0 + 1 < deg) ? ((uint)p1 & 0x1FFFF) : (uint)i;
                uint s2 = (e0 + 2 < deg) ? ((uint)p2 & 0x1FFFF) : (uint)i;
                uint s3 = (e0 + 3 < deg) ? ((uint)p3 & 0x1FFFF) : (uint)i;
                uint s4 = (e0 + 4 < deg) ? ((uint)p4 & 0x1FFFF) : (uint)i;
                uint s5 = (e0 + 5 < deg) ? ((uint)p5 & 0x1FFFF) : (uint)i;
                uint s6 = (e0 + 6 < deg) ? ((uint)p6 & 0x1FFFF) : (uint)i;
                uint s7 = (e0 + 7 < deg) ? ((uint)p7 & 0x1FFFF) : (uint)i;
                float v0 = (float)in[(size_t)s0 * CH + lane];
                float v1 = (float)in[(size_t)s1 * CH + lane];
                float v2 = (float)in[(size_t)s2 * CH + lane];
                float v3 = (float)in[(size_t)s3 * CH + lane];
                float v4 = (float)in[(size_t)s4 * CH + lane];
                float v5 = (float)in[(size_t)s5 * CH + lane];
                float v6 = (float)in[(size_t)s6 * CH + lane];
                float v7 = (float)in[(size_t)s7 * CH + lane];
#define LAD(J, PJ, VJ)                                                          \
                if (e0 + J < deg) {                                             \
                    int r = (PJ) >> 17;                                         \
                    if (r == 0)      { a0 += (VJ); c0++; }                      \
                    else if (r == 1) { a1 += (VJ); c1++; }                      \
                    else if (r == 2) { a2 += (VJ); c2++; }                      \
                    else if (r == 3) { a3 += (VJ); c3++; }                      \
                    else             { a4 += (VJ); c4++; }                      \
                }
                LAD(0, p0, v0) LAD(1, p1, v1) LAD(2, p2, v2) LAD(3, p3, v3)
                LAD(4, p4, v4) LAD(5, p5, v5) LAD(6, p6, v6) LAD(7, p7, v7)
#undef LAD
                pka = nxa; pkb = nxb;
            }
        }

        float i0 = 1.0f / (float)(c0 > 0 ? c0 : 1);
        float i1 = 1.0f / (float)(c1 > 0 ? c1 : 1);
        float i2 = 1.0f / (float)(c2 > 0 ? c2 : 1);
        float i3 = 1.0f / (float)(c3 > 0 ? c3 : 1);
        float i4 = 1.0f / (float)(c4 > 0 ? c4 : 1);

        arow[0 * 64 + lane] = (f16)self;
        arow[1 * 64 + lane] = (f16)(a0 * i0);
        arow[2 * 64 + lane] = (f16)(a1 * i1);
        arow[3 * 64 + lane] = (f16)(a2 * i2);
        arow[4 * 64 + lane] = (f16)(a3 * i3);
        arow[5 * 64 + lane] = (f16)(a4 * i4);
    }
    __syncthreads();

    // ---- phase 2: MFMA. wave w -> N-tile w (cols w*16..w*16+15) ----
    const int col = lane & 15, lg = lane >> 4;
    float bv = bias[wv * 16 + col];
    f32x4 acc = {bv, bv, bv, bv};
    const char* Ab = (const char*)Ap + col * 784 + lg * 16;
    const char* Bb = (const char*)Btg + (size_t)(wv * 16 + col) * 768 + lg * 16;
#pragma unroll
    for (int k = 0; k < KTOT / 32; ++k) {
        f16x8 af = *(const f16x8*)(Ab + k * 64);
        f16x8 bf = *(const f16x8*)(Bb + k * 64);
        acc = __builtin_amdgcn_mfma_f32_16x16x32_f16(af, bf, acc, 0, 0, 0);
    }

    if (!CLS) {
#pragma unroll
        for (int r = 0; r < 4; ++r) {
            int node = nb0 + lg * 4 + r;
            if (node < NN)
                outh[(size_t)node * CH + wv * 16 + col] = (f16)fmaxf(acc[r], 0.f);
        }
    } else {
        __syncthreads();  // all Ap reads done -> safe to reuse smem as h-stage
        float* hst = (float*)smem;  // [16][HPAD]
#pragma unroll
        for (int r = 0; r < 4; ++r) {
            int nl = lg * 4 + r;
            int node = nb0 + nl;
            hst[nl * HPAD + wv * 16 + col] = acc[r];
            if (node < NN)
                outf[(size_t)node * CH + wv * 16 + col] = acc[r];
        }
        __syncthreads();
        // classifier: wave handles 4 nodes; Wc/bc read from global (L2-resident)
        float wcr[NCLS];
#pragma unroll
        for (int c = 0; c < NCLS; ++c) wcr[c] = Wc[lane * NCLS + c];
        for (int q = 0; q < 4; ++q) {
            int nl = wv * 4 + q;
            int i = nb0 + nl;
            if (i >= NN) continue;
            float v = hst[nl * HPAD + lane];
            float p[NCLS];
#pragma unroll
            for (int c = 0; c < NCLS; ++c) p[c] = v * wcr[c];
#pragma unroll
            for (int off = 32; off > 0; off >>= 1) {
#pragma unroll
                for (int c = 0; c < NCLS; ++c) p[c] += __shfl_xor(p[c], off);
            }
            if (lane == 0) {
                float4 lo = make_float4(p[0] + bc[0], p[1] + bc[1], p[2] + bc[2], p[3] + bc[3]);
                float4 hi = make_float4(p[4] + bc[4], p[5] + bc[5], p[6] + bc[6], p[7] + bc[7]);
                *reinterpret_cast<float4*>(&logits[(size_t)i * NCLS]) = lo;
                *reinterpret_cast<float4*>(&logits[(size_t)i * NCLS + 4]) = hi;
            }
        }
    }
}

extern "C" void kernel_launch(void* const* d_in, const int* in_sizes, int n_in,
                              void* d_out, int out_size, void* d_ws, size_t ws_size,
                              hipStream_t stream) {
    const float* x     = (const float*)d_in[0];
    const int*   ei    = (const int*)d_in[1];
    const int*   et    = (const int*)d_in[2];
    const float* W1    = (const float*)d_in[3];
    const float* root1 = (const float*)d_in[4];
    const float* b1    = (const float*)d_in[5];
    const float* W2    = (const float*)d_in[6];
    const float* root2 = (const float*)d_in[7];
    const float* b2    = (const float*)d_in[8];
    const float* Wc    = (const float*)d_in[9];
    const float* bc    = (const float*)d_in[10];
    const int* src = ei;
    const int* dst = ei + NE;

    float* h2     = (float*)d_out;            // [NN][CH]
    float* logits = h2 + (size_t)NN * CH;     // [NN][NCLS]

    int* cursor = (int*)d_ws;                                   // [NN]
    int* sorted = cursor + NN;                                  // [NN][SLOT] + 16 slack
    f16* h1h    = (f16*)(sorted + (size_t)NN * SLOT + 16);      // [NN][CH]
    f16* xh     = h1h + (size_t)NN * CH;                        // [NN][CH]
    f16* Btg    = xh + (size_t)NN * CH;                         // [2][64][KTOT]

    (void)hipMemsetAsync(cursor, 0, (size_t)NN * 4, stream);
    cvt_f16_kernel<<<(NN * CH / 4 + 255) / 256, 256, 0, stream>>>(x, xh);
    scatter_kernel<<<(NE + 255) / 256, 256, 0, stream>>>(src, dst, et, cursor, sorted);
    prep_weights<<<(2 * 64 * KTOT + 255) / 256, 256, 0, stream>>>(root1, W1, root2, W2, Btg);

    int nBlk = (NN + 15) / 16;  // 6250
    fused_layer2<false><<<nBlk, 256, 0, stream>>>(
        xh, Btg, b1, cursor, sorted, nullptr, h1h, nullptr, nullptr, nullptr);
    fused_layer2<true><<<nBlk, 256, 0, stream>>>(
        h1h, Btg + (size_t)64 * KTOT, b2, cursor, sorted, h2, nullptr, Wc, bc, logits);
}